// Round 5
// baseline (724.250 us; speedup 1.0000x reference)
//
#include <hip/hip_runtime.h>
#include <stdint.h>

typedef __attribute__((ext_vector_type(8))) short short8;
typedef __attribute__((ext_vector_type(4))) float f32x4;
typedef __attribute__((ext_vector_type(2))) unsigned int uint2v;

#define C0 228
#define C1 111
#define C2 51
#define KP 448           // padded channels: [0,256)=b0, [256,384)=b1, [384,448)=b2
#define RS 456           // LDS row stride (bf16 elems)
#define NPIX 64
#define BUFE (NPIX * RS) // elems per LDS buffer
#define DYN_LDS (2 * BUFE * 2)  // 116736 B double buffer

__device__ __forceinline__ unsigned short f2bf(float f) {
  unsigned u = __float_as_uint(f);
  u += 0x7FFFu + ((u >> 16) & 1u);          // RNE
  return (unsigned short)(u >> 16);
}
__device__ __forceinline__ float bf2f(unsigned v) {
  return __uint_as_float(v << 16);
}
__device__ __forceinline__ int out_chan(int c) {
  if (c < 228) return c;
  if (c < 256) return -1;
  if (c < 367) return 228 + (c - 256);
  if (c < 384) return -1;
  if (c < 435) return 339 + (c - 384);
  return -1;
}

// lgkm-only barrier: order LDS without draining outstanding global loads.
__device__ __forceinline__ void barrier_lgkm() {
  __builtin_amdgcn_sched_barrier(0);
  asm volatile("s_waitcnt lgkmcnt(0)" ::: "memory");
  __builtin_amdgcn_s_barrier();
  __builtin_amdgcn_sched_barrier(0);
}

// ---- prep: padded blocked weight matrix Wrow[KP][KP] bf16 + summed bias ----
__global__ void crf_prep(
    const float* __restrict__ w01, const float* __restrict__ w02,
    const float* __restrict__ w10, const float* __restrict__ w12,
    const float* __restrict__ w20, const float* __restrict__ w21,
    const float* __restrict__ b01, const float* __restrict__ b02,
    const float* __restrict__ b10, const float* __restrict__ b12,
    const float* __restrict__ b20, const float* __restrict__ b21,
    unsigned short* __restrict__ Wrow, float* __restrict__ bbig) {
  int idx = blockIdx.x * 256 + threadIdx.x;
  if (idx >= KP * KP) return;
  int m = idx / KP;
  int k = idx - m * KP;
  int bm, lm, bk, lk, Ck;
  bool mr, kr;
  if (m < 256)      { bm = 0; lm = m;       mr = lm < C0; }
  else if (m < 384) { bm = 1; lm = m - 256; mr = lm < C1; }
  else              { bm = 2; lm = m - 384; mr = lm < C2; }
  if (k < 256)      { bk = 0; lk = k;       Ck = C0; kr = lk < C0; }
  else if (k < 384) { bk = 1; lk = k - 256; Ck = C1; kr = lk < C1; }
  else              { bk = 2; lk = k - 384; Ck = C2; kr = lk < C2; }
  float v = 0.f;
  if (bm != bk && mr && kr) {
    const float* w;
    if (bk == 0)      w = (bm == 1) ? w01 : w02;
    else if (bk == 1) w = (bm == 0) ? w10 : w12;
    else              w = (bm == 0) ? w20 : w21;
    v = w[lm * Ck + lk];
  }
  Wrow[idx] = f2bf(v);
  if (idx < KP) {
    float bv = 0.f;
    int c = idx;
    if (c < 228)                  bv = b10[c] + b20[c];
    else if (c >= 256 && c < 367) bv = b01[c - 256] + b21[c - 256];
    else if (c >= 384 && c < 435) bv = b02[c - 384] + b12[c - 384];
    bbig[idx] = bv;
  }
}

// ---- producer: nt-load x (fp32) -> bf16 pack -> LDS. pw=0..3, lane=pixel. ----
// channel-group index = pw*14 + G0 + g, 8 channels each (56 groups total).
template <int NG, int G0>
__device__ __forceinline__ void produce(int pw, int lane, int b, int pp,
    const float* __restrict__ x0, const float* __restrict__ x1,
    const float* __restrict__ x2, unsigned short* __restrict__ nxt) {
  float v[NG][8];
  #pragma unroll
  for (int g = 0; g < NG; ++g) {
    const int c0 = (pw * 14 + G0 + g) * 8;
    #pragma unroll
    for (int cc = 0; cc < 8; ++cc) {
      const int c = c0 + cc;
      float t = 0.f;
      if (c < 228)
        t = __builtin_nontemporal_load(x0 + (((size_t)(b * C0 + c)) << 16) + pp + lane);
      else if (c >= 256 && c < 367)
        t = __builtin_nontemporal_load(x1 + (((size_t)(b * C1 + (c - 256))) << 16) + pp + lane);
      else if (c >= 384 && c < 435)
        t = __builtin_nontemporal_load(x2 + (((size_t)(b * C2 + (c - 384))) << 16) + pp + lane);
      v[g][cc] = t;
    }
  }
  #pragma unroll
  for (int g = 0; g < NG; ++g) {
    const int c0 = (pw * 14 + G0 + g) * 8;
    short8 pk;
    #pragma unroll
    for (int cc = 0; cc < 8; ++cc) pk[cc] = (short)f2bf(v[g][cc]);
    *reinterpret_cast<short8*>(nxt + lane * RS + c0) = pk;
  }
}

// ---- consumer K-loop (R3-proven): weights streamed from L2, h from LDS ----
__device__ __forceinline__ void kloop(const unsigned short* __restrict__ cur,
                                      const unsigned short* __restrict__ Wrow,
                                      f32x4 (&acc)[4][4], int wave, bool has3,
                                      int l15, int lq) {
  #pragma unroll
  for (int ks = 0; ks < 14; ++ks) {
    const int kb = (ks < 8) ? 0 : ((ks < 12) ? 1 : 2);
    const int kcol = ks * 32 + (lq << 3);
    short8 bq[4];
    #pragma unroll
    for (int n = 0; n < 4; ++n)
      bq[n] = *reinterpret_cast<const short8*>(cur + (n * 16 + l15) * RS + kcol);
    #pragma unroll
    for (int t = 0; t < 4; ++t) {
      const int bm = (t < 2) ? 0 : ((t < 3) ? 1 : 2);
      if (bm == kb) continue;
      if (t == 3 && !has3) continue;
      const int mt = wave + 8 * t;
      const short8 aq = *reinterpret_cast<const short8*>(
          Wrow + (mt * 16 + l15) * KP + kcol);
      #pragma unroll
      for (int n = 0; n < 4; ++n)
        acc[t][n] =
            __builtin_amdgcn_mfma_f32_16x16x32_bf16(aq, bq[n], acc[t][n], 0, 0, 0);
    }
  }
}

// ---- main: 256 persistent wgs x 768 thr (8 consumer + 4 producer waves),
//      8 pixel-tiles each, double-buffered LDS, 3 lgkm-barriers per tile ----
__global__ __launch_bounds__(768, 3) void crf_main(
    const float* __restrict__ x0, const float* __restrict__ x1,
    const float* __restrict__ x2,
    const unsigned short* __restrict__ Wrow,
    const float* __restrict__ bbig,
    const float* __restrict__ pa,
    float* __restrict__ out) {
  extern __shared__ unsigned short hbuf[];
  const int lane = threadIdx.x & 63;
  const int wave = threadIdx.x >> 6;
  const bool is_cons = (wave < 8);
  const int pw = wave - 8;                  // producer wave id 0..3
  const int l15 = lane & 15;
  const int lq = lane >> 4;
  const float apar = pa[0];
  const bool has3 = (wave < 4);

  const int T0 = blockIdx.x * 8;            // 8 consecutive 64-px tiles
  const int b = (T0 >= 1024) ? 1 : 0;       // 128 wgs per image, never straddles
  const int ppbase = (T0 & 1023) << 6;

  // prologue: producers stage tile 0 into buffer 0
  if (!is_cons) {
    produce<5, 0>(pw, lane, b, ppbase, x0, x1, x2, hbuf);
    produce<5, 5>(pw, lane, b, ppbase, x0, x1, x2, hbuf);
    produce<4, 10>(pw, lane, b, ppbase, x0, x1, x2, hbuf);
  }
  barrier_lgkm();

  for (int i = 0; i < 8; ++i) {
    unsigned short* cur = hbuf + (i & 1) * BUFE;
    unsigned short* nxt = hbuf + ((i + 1) & 1) * BUFE;
    const int pp0 = ppbase + (i << 6);
    const int pp1 = pp0 + 64;
    const bool more = (i < 7);

    f32x4 acc[4][4];

    // ---- phase A: consumers kloop iter0(cur); producers stage part 1 ----
    if (is_cons) {
      #pragma unroll
      for (int t = 0; t < 4; ++t)
        #pragma unroll
        for (int n = 0; n < 4; ++n) acc[t][n] = (f32x4){0.f, 0.f, 0.f, 0.f};
      kloop(cur, Wrow, acc, wave, has3, l15, lq);
    } else if (more) {
      produce<5, 0>(pw, lane, b, pp1, x0, x1, x2, nxt);
    }
    barrier_lgkm();   // iter0 reads of cur complete

    // ---- phase B: consumers h1 writeback (in place); producers part 2 ----
    if (is_cons) {
      #pragma unroll
      for (int t = 0; t < 4; ++t) {
        if (t == 3 && !has3) continue;
        const int cb = (wave + 8 * t) * 16 + (lq << 2);
        const f32x4 bias = *reinterpret_cast<const f32x4*>(bbig + cb);
        #pragma unroll
        for (int n = 0; n < 4; ++n) {
          const int p = n * 16 + l15;
          uint2v ho = *reinterpret_cast<const uint2v*>(cur + p * RS + cb);
          const float hof[4] = {bf2f(ho[0] & 0xFFFFu), bf2f(ho[0] >> 16),
                                bf2f(ho[1] & 0xFFFFu), bf2f(ho[1] >> 16)};
          unsigned short nb[4];
          #pragma unroll
          for (int r = 0; r < 4; ++r) {
            float v = acc[t][n][r] + bias[r];
            float pr = (v >= 0.f) ? v : apar * v;
            nb[r] = f2bf(fmaxf(hof[r] + pr, 0.f));
          }
          uint2v pwv;
          pwv[0] = (unsigned)nb[0] | ((unsigned)nb[1] << 16);
          pwv[1] = (unsigned)nb[2] | ((unsigned)nb[3] << 16);
          *reinterpret_cast<uint2v*>(cur + p * RS + cb) = pwv;
        }
      }
    } else if (more) {
      produce<5, 5>(pw, lane, b, pp1, x0, x1, x2, nxt);
    }
    barrier_lgkm();   // h1 visible to all consumer waves

    // ---- phase C: consumers kloop iter1 + epilogue stores; producers part 3 ----
    if (is_cons) {
      #pragma unroll
      for (int t = 0; t < 4; ++t)
        #pragma unroll
        for (int n = 0; n < 4; ++n) acc[t][n] = (f32x4){0.f, 0.f, 0.f, 0.f};
      kloop(cur, Wrow, acc, wave, has3, l15, lq);
      #pragma unroll
      for (int t = 0; t < 4; ++t) {
        if (t == 3 && !has3) continue;
        const int cb = (wave + 8 * t) * 16 + (lq << 2);
        const f32x4 bias = *reinterpret_cast<const f32x4*>(bbig + cb);
        #pragma unroll
        for (int n = 0; n < 4; ++n) {
          const int p = n * 16 + l15;
          uint2v ho = *reinterpret_cast<const uint2v*>(cur + p * RS + cb);
          const float hof[4] = {bf2f(ho[0] & 0xFFFFu), bf2f(ho[0] >> 16),
                                bf2f(ho[1] & 0xFFFFu), bf2f(ho[1] >> 16)};
          #pragma unroll
          for (int r = 0; r < 4; ++r) {
            const int c = cb + r;
            const int o = out_chan(c);
            float v = acc[t][n][r] + bias[r];
            float pr = (v >= 0.f) ? v : apar * v;
            float hn = fmaxf(hof[r] + pr, 0.f);
            if (o >= 0)
              __builtin_nontemporal_store(
                  hn, out + (((size_t)(b * 390 + o)) << 16) + pp0 + p);
          }
        }
      }
    } else if (more) {
      produce<4, 10>(pw, lane, b, pp1, x0, x1, x2, nxt);
    }
    barrier_lgkm();   // nxt fully staged; cur free for overwrite next tile
  }
}

extern "C" void kernel_launch(void* const* d_in, const int* in_sizes, int n_in,
                              void* d_out, int out_size, void* d_ws, size_t ws_size,
                              hipStream_t stream) {
  const float* x0  = (const float*)d_in[0];
  const float* x1  = (const float*)d_in[1];
  const float* x2  = (const float*)d_in[2];
  const float* w01 = (const float*)d_in[3];
  const float* b01 = (const float*)d_in[4];
  const float* w02 = (const float*)d_in[5];
  const float* b02 = (const float*)d_in[6];
  const float* w10 = (const float*)d_in[7];
  const float* b10 = (const float*)d_in[8];
  const float* w12 = (const float*)d_in[9];
  const float* b12 = (const float*)d_in[10];
  const float* w20 = (const float*)d_in[11];
  const float* b20 = (const float*)d_in[12];
  const float* w21 = (const float*)d_in[13];
  const float* b21 = (const float*)d_in[14];
  const float* pa  = (const float*)d_in[15];

  unsigned short* Wrow = (unsigned short*)d_ws;                 // 448*448*2 B
  float* bbig = (float*)((char*)d_ws + (size_t)KP * KP * 2);    // +1792 B

  hipFuncSetAttribute((const void*)crf_main,
                      hipFuncAttributeMaxDynamicSharedMemorySize, DYN_LDS);

  crf_prep<<<dim3((KP * KP + 255) / 256), dim3(256), 0, stream>>>(
      w01, w02, w10, w12, w20, w21, b01, b02, b10, b12, b20, b21, Wrow, bbig);
  crf_main<<<dim3(256), dim3(768), DYN_LDS, stream>>>(x0, x1, x2, Wrow, bbig, pa,
                                                      (float*)d_out);
}

// Round 6
// 464.461 us; speedup vs baseline: 1.5593x; 1.5593x over previous
//
#include <hip/hip_runtime.h>
#include <stdint.h>

typedef __attribute__((ext_vector_type(8))) short short8;
typedef __attribute__((ext_vector_type(4))) float f32x4;
typedef __attribute__((ext_vector_type(2))) unsigned int uint2v;

#define C0 228
#define C1 111
#define C2 51
#define KP 448            // padded channels: [0,256)=b0, [256,384)=b1, [384,448)=b2
#define RS 458            // LDS row stride in bf16 elems; 229 dwords (odd) -> conflict-free rows
#define NPIX 64
#define BUFE (NPIX * RS)  // elems per LDS buffer
#define DYN_LDS (2 * BUFE * 2)   // 117248 B double buffer (1 wg/CU)
#define NCHUNK (28 * 14)  // (mt, ks) weight chunks, 1KB each

__device__ __forceinline__ unsigned short f2bf(float f) {
  unsigned u = __float_as_uint(f);
  u += 0x7FFFu + ((u >> 16) & 1u);          // RNE
  return (unsigned short)(u >> 16);
}
__device__ __forceinline__ float bf2f(unsigned v) {
  return __uint_as_float(v << 16);
}
__device__ __forceinline__ int out_chan(int c) {
  if (c < 228) return c;
  if (c < 256) return -1;
  if (c < 367) return 228 + (c - 256);
  if (c < 384) return -1;
  if (c < 435) return 339 + (c - 384);
  return -1;
}

// lgkm-only barrier: order LDS without draining outstanding global stores.
__device__ __forceinline__ void barrier_lgkm() {
  __builtin_amdgcn_sched_barrier(0);
  asm volatile("s_waitcnt lgkmcnt(0)" ::: "memory");
  __builtin_amdgcn_s_barrier();
  __builtin_amdgcn_sched_barrier(0);
}

// ---- prep: weights -> fragment-contiguous bf16 chunks Wfrag[mt*14+ks][512],
//      lane l holds A[row = l&15][k = ks*32 + (l>>4)*8 + el]; + summed bias ----
__global__ void crf_prep(
    const float* __restrict__ w01, const float* __restrict__ w02,
    const float* __restrict__ w10, const float* __restrict__ w12,
    const float* __restrict__ w20, const float* __restrict__ w21,
    const float* __restrict__ b01, const float* __restrict__ b02,
    const float* __restrict__ b10, const float* __restrict__ b12,
    const float* __restrict__ b20, const float* __restrict__ b21,
    unsigned short* __restrict__ Wfrag, float* __restrict__ bbig) {
  int idx = blockIdx.x * 256 + threadIdx.x;   // 784 blocks = 28*14*512 / 256
  if (idx < KP) {
    float bv = 0.f;
    int c = idx;
    if (c < 228)                  bv = b10[c] + b20[c];
    else if (c >= 256 && c < 367) bv = b01[c - 256] + b21[c - 256];
    else if (c >= 384 && c < 435) bv = b02[c - 384] + b12[c - 384];
    bbig[idx] = bv;
  }
  if (idx >= NCHUNK * 512) return;
  const int ch = idx >> 9;                    // chunk 0..391
  const int e  = idx & 511;
  const int mt = ch / 14;
  const int ks = ch - mt * 14;
  const int lane = e >> 3, el = e & 7;
  const int m = mt * 16 + (lane & 15);
  const int k = ks * 32 + (lane >> 4) * 8 + el;

  int bm, lm, bk, lk, Ck;
  bool mr, kr;
  if (m < 256)      { bm = 0; lm = m;       mr = lm < C0; }
  else if (m < 384) { bm = 1; lm = m - 256; mr = lm < C1; }
  else              { bm = 2; lm = m - 384; mr = lm < C2; }
  if (k < 256)      { bk = 0; lk = k;       Ck = C0; kr = lk < C0; }
  else if (k < 384) { bk = 1; lk = k - 256; Ck = C1; kr = lk < C1; }
  else              { bk = 2; lk = k - 384; Ck = C2; kr = lk < C2; }
  float v = 0.f;
  if (bm != bk && mr && kr) {
    const float* wp;
    if (bk == 0)      wp = (bm == 1) ? w01 : w02;
    else if (bk == 1) wp = (bm == 0) ? w10 : w12;
    else              wp = (bm == 0) ? w20 : w21;
    v = wp[lm * Ck + lk];
  }
  Wfrag[idx] = f2bf(v);
}

// ---- stage: issue 56 nt-loads into regs (early), convert+ds_write (late) ----
__device__ __forceinline__ void stage_load(int wave, int lane, int b, int pp,
    const float* __restrict__ x0, const float* __restrict__ x1,
    const float* __restrict__ x2, float (*sv)[8]) {
  #pragma unroll
  for (int g = 0; g < 7; ++g) {
    const int c0 = (wave + 8 * g) * 8;
    #pragma unroll
    for (int cc = 0; cc < 8; ++cc) {
      const int c = c0 + cc;
      float t = 0.f;
      if (c < 228)
        t = __builtin_nontemporal_load(x0 + (((size_t)(b * C0 + c)) << 16) + pp + lane);
      else if (c >= 256 && c < 367)
        t = __builtin_nontemporal_load(x1 + (((size_t)(b * C1 + (c - 256))) << 16) + pp + lane);
      else if (c >= 384 && c < 435)
        t = __builtin_nontemporal_load(x2 + (((size_t)(b * C2 + (c - 384))) << 16) + pp + lane);
      sv[g][cc] = t;
    }
  }
}

__device__ __forceinline__ void stage_write(int wave, int lane, float (*sv)[8],
                                            unsigned short* __restrict__ dst) {
  #pragma unroll
  for (int g = 0; g < 7; ++g) {
    const int c0 = (wave + 8 * g) * 8;
    short8 pk;
    #pragma unroll
    for (int cc = 0; cc < 8; ++cc) pk[cc] = (short)f2bf(sv[g][cc]);
    *reinterpret_cast<short8*>(dst + lane * RS + c0) = pk;
  }
}

// ---- K-loop: fragment-contiguous weights (L2) x LDS h fragments ----
__device__ __forceinline__ void kloop(const unsigned short* __restrict__ cur,
                                      const unsigned short* __restrict__ Wfrag,
                                      f32x4 (&acc)[4][4], int wave, bool has3,
                                      int lane, int l15, int lq) {
  #pragma unroll
  for (int ks = 0; ks < 14; ++ks) {
    const int kb = (ks < 8) ? 0 : ((ks < 12) ? 1 : 2);
    const int kcol = ks * 32 + (lq << 3);
    short8 bq[4];
    #pragma unroll
    for (int n = 0; n < 4; ++n)
      bq[n] = *reinterpret_cast<const short8*>(cur + (n * 16 + l15) * RS + kcol);
    #pragma unroll
    for (int t = 0; t < 4; ++t) {
      const int bm = (t < 2) ? 0 : ((t < 3) ? 1 : 2);
      if (bm == kb) continue;           // diagonal (zero) block: skip
      if (t == 3 && !has3) continue;    // waves 4..7: no 4th tile
      const int mt = wave + 8 * t;
      const short8 aq = *reinterpret_cast<const short8*>(
          Wfrag + (((size_t)(mt * 14 + ks)) << 9) + (lane << 3));
      #pragma unroll
      for (int n = 0; n < 4; ++n)
        acc[t][n] =
            __builtin_amdgcn_mfma_f32_16x16x32_bf16(aq, bq[n], acc[t][n], 0, 0, 0);
    }
  }
}

// ---- main: 256 persistent wgs x 512 thr (8 waves), 8 tiles each, dbuf LDS.
//      Stage loads issued before kloop0; consumed after; lgkm barrier at tile end
//      so epilogue stores drain in background. ----
__global__ __launch_bounds__(512, 2) void crf_main(
    const float* __restrict__ x0, const float* __restrict__ x1,
    const float* __restrict__ x2,
    const unsigned short* __restrict__ Wfrag,
    const float* __restrict__ bbig,
    const float* __restrict__ pa,
    float* __restrict__ out) {
  extern __shared__ unsigned short hbuf[];
  const int lane = threadIdx.x & 63;
  const int wave = threadIdx.x >> 6;
  const int l15 = lane & 15;
  const int lq = lane >> 4;
  const float apar = pa[0];
  const bool has3 = (wave < 4);

  const int bid = blockIdx.x;
  const int b = (bid >= 128) ? 1 : 0;       // 128 wgs per image
  const int ppbase = (bid & 127) << 9;      // 512 px per wg (8 x 64-px tiles)

  float sv[7][8];

  // prologue: stage tile 0 into buffer 0
  stage_load(wave, lane, b, ppbase, x0, x1, x2, sv);
  stage_write(wave, lane, sv, hbuf);
  __syncthreads();

  for (int i = 0; i < 8; ++i) {
    unsigned short* cur = hbuf + (i & 1) * BUFE;
    unsigned short* nxt = hbuf + ((i + 1) & 1) * BUFE;
    const int pp0 = ppbase + (i << 6);
    const bool more = (i < 7);

    // issue next tile's loads early (hide under kloop0)
    if (more) stage_load(wave, lane, b, pp0 + 64, x0, x1, x2, sv);

    // --- iter 0 ---
    f32x4 acc[4][4];
    #pragma unroll
    for (int t = 0; t < 4; ++t)
      #pragma unroll
      for (int n = 0; n < 4; ++n) acc[t][n] = (f32x4){0.f, 0.f, 0.f, 0.f};
    kloop(cur, Wfrag, acc, wave, has3, lane, l15, lq);

    if (more) stage_write(wave, lane, sv, nxt);  // waits only its own loads
    __syncthreads();   // iter0 reads of cur done; nxt staged

    // --- h1 = relu(h0 + prelu(binary + bias)) in place (own channels) ---
    #pragma unroll
    for (int t = 0; t < 4; ++t) {
      if (t == 3 && !has3) continue;
      const int cb = (wave + 8 * t) * 16 + (lq << 2);
      const f32x4 bias = *reinterpret_cast<const f32x4*>(bbig + cb);
      #pragma unroll
      for (int n = 0; n < 4; ++n) {
        const int p = n * 16 + l15;
        uint2v ho = *reinterpret_cast<const uint2v*>(cur + p * RS + cb);
        const float hof[4] = {bf2f(ho[0] & 0xFFFFu), bf2f(ho[0] >> 16),
                              bf2f(ho[1] & 0xFFFFu), bf2f(ho[1] >> 16)};
        unsigned short nb[4];
        #pragma unroll
        for (int r = 0; r < 4; ++r) {
          float v = acc[t][n][r] + bias[r];
          float pr = (v >= 0.f) ? v : apar * v;
          nb[r] = f2bf(fmaxf(hof[r] + pr, 0.f));
        }
        uint2v pw;
        pw[0] = (unsigned)nb[0] | ((unsigned)nb[1] << 16);
        pw[1] = (unsigned)nb[2] | ((unsigned)nb[3] << 16);
        *reinterpret_cast<uint2v*>(cur + p * RS + cb) = pw;
      }
    }
    __syncthreads();   // h1 visible to all waves

    // --- iter 1 + epilogue ---
    #pragma unroll
    for (int t = 0; t < 4; ++t)
      #pragma unroll
      for (int n = 0; n < 4; ++n) acc[t][n] = (f32x4){0.f, 0.f, 0.f, 0.f};
    kloop(cur, Wfrag, acc, wave, has3, lane, l15, lq);

    #pragma unroll
    for (int t = 0; t < 4; ++t) {
      if (t == 3 && !has3) continue;
      const int cb = (wave + 8 * t) * 16 + (lq << 2);
      const f32x4 bias = *reinterpret_cast<const f32x4*>(bbig + cb);
      #pragma unroll
      for (int n = 0; n < 4; ++n) {
        const int p = n * 16 + l15;
        uint2v ho = *reinterpret_cast<const uint2v*>(cur + p * RS + cb);
        const float hof[4] = {bf2f(ho[0] & 0xFFFFu), bf2f(ho[0] >> 16),
                              bf2f(ho[1] & 0xFFFFu), bf2f(ho[1] >> 16)};
        #pragma unroll
        for (int r = 0; r < 4; ++r) {
          const int c = cb + r;
          const int o = out_chan(c);
          float v = acc[t][n][r] + bias[r];
          float pr = (v >= 0.f) ? v : apar * v;
          float hn = fmaxf(hof[r] + pr, 0.f);
          if (o >= 0)
            __builtin_nontemporal_store(
                hn, out + (((size_t)(b * 390 + o)) << 16) + pp0 + p);
        }
      }
    }

    // lgkm-only: LDS ordering for buffer swap WITHOUT draining epilogue stores
    barrier_lgkm();
  }
}

extern "C" void kernel_launch(void* const* d_in, const int* in_sizes, int n_in,
                              void* d_out, int out_size, void* d_ws, size_t ws_size,
                              hipStream_t stream) {
  const float* x0  = (const float*)d_in[0];
  const float* x1  = (const float*)d_in[1];
  const float* x2  = (const float*)d_in[2];
  const float* w01 = (const float*)d_in[3];
  const float* b01 = (const float*)d_in[4];
  const float* w02 = (const float*)d_in[5];
  const float* b02 = (const float*)d_in[6];
  const float* w10 = (const float*)d_in[7];
  const float* b10 = (const float*)d_in[8];
  const float* w12 = (const float*)d_in[9];
  const float* b12 = (const float*)d_in[10];
  const float* w20 = (const float*)d_in[11];
  const float* b20 = (const float*)d_in[12];
  const float* w21 = (const float*)d_in[13];
  const float* b21 = (const float*)d_in[14];
  const float* pa  = (const float*)d_in[15];

  unsigned short* Wfrag = (unsigned short*)d_ws;                // 392 KB
  float* bbig = (float*)((char*)d_ws + (size_t)NCHUNK * 512 * 2);

  hipFuncSetAttribute((const void*)crf_main,
                      hipFuncAttributeMaxDynamicSharedMemorySize, DYN_LDS);

  crf_prep<<<dim3((NCHUNK * 512) / 256), dim3(256), 0, stream>>>(
      w01, w02, w10, w12, w20, w21, b01, b02, b10, b12, b20, b21, Wfrag, bbig);
  crf_main<<<dim3(256), dim3(512), DYN_LDS, stream>>>(x0, x1, x2, Wfrag, bbig, pa,
                                                      (float*)d_out);
}

// Round 7
// 358.320 us; speedup vs baseline: 2.0212x; 1.2962x over previous
//
#include <hip/hip_runtime.h>
#include <stdint.h>

typedef __attribute__((ext_vector_type(8))) short short8;
typedef __attribute__((ext_vector_type(4))) float f32x4;
typedef __attribute__((ext_vector_type(2))) unsigned int uint2v;

#define C0 228
#define C1 111
#define C2 51
#define KP 448            // padded channels: [0,256)=b0, [256,384)=b1, [384,448)=b2
#define RS 458            // LDS row stride in bf16 elems; 229 dwords (odd) -> conflict-free
#define NPIX 64

// ---- static (tile,ks) chunk schedule: 224 chunks = 8 waves x 28 slots ----
// tiles: 0-15 = b0, 16-23 = b1, 24-27 = b2. ks: 0-7 = b0, 8-11 = b1, 12-13 = b2.
// waves 0-3 (class A): tiles {3w, 3w+1, 3w+2 (b0), 16+w (b1)}
// waves 4-7 (class B): tiles {8+w (b0), 16+w (b1), 20+w (b2)}
constexpr int A_KS[28] = {0,1,2,3,4,5,6,7,8,8,8,9,9,9,10,10,10,11,11,11,12,12,12,12,13,13,13,13};
constexpr int A_T [28] = {3,3,3,3,3,3,3,3,0,1,2,0,1,2, 0, 1, 2, 0, 1, 2, 0, 1, 2, 3, 0, 1, 2, 3};
constexpr int B_KS[28] = {0,0,1,1,2,2,3,3,4,4,5,5,6,6,7,7,8,8,9,9,10,10,11,11,12,12,13,13};
constexpr int B_T [28] = {1,2,1,2,1,2,1,2,1,2,1,2,1,2,1,2,0,2,0,2, 0, 2, 0, 2, 0, 1, 0, 1};

__host__ __device__ constexpr int tile_id(int w, int t) {
  return (w < 4) ? ((t < 3) ? (3 * w + t) : (16 + w))
                 : ((t == 0) ? (8 + w) : (t == 1) ? (16 + w) : (20 + w));
}

__device__ __forceinline__ unsigned short f2bf(float f) {
  unsigned u = __float_as_uint(f);
  u += 0x7FFFu + ((u >> 16) & 1u);          // RNE
  return (unsigned short)(u >> 16);
}
__device__ __forceinline__ float bf2f(unsigned v) {
  return __uint_as_float(v << 16);
}
__device__ __forceinline__ int out_chan(int c) {
  if (c < 228) return c;
  if (c < 256) return -1;
  if (c < 367) return 228 + (c - 256);
  if (c < 384) return -1;
  if (c < 435) return 339 + (c - 384);
  return -1;
}

// ---- prep: weights -> schedule-ordered fragment-contiguous 1KB chunks
//      Wfrag[(w*28+s)*512 + lane*8 + el], + summed bias (R4-verified) ----
__global__ void crf_prep(
    const float* __restrict__ w01, const float* __restrict__ w02,
    const float* __restrict__ w10, const float* __restrict__ w12,
    const float* __restrict__ w20, const float* __restrict__ w21,
    const float* __restrict__ b01, const float* __restrict__ b02,
    const float* __restrict__ b10, const float* __restrict__ b12,
    const float* __restrict__ b20, const float* __restrict__ b21,
    unsigned short* __restrict__ Wfrag, float* __restrict__ bbig) {
  int idx = blockIdx.x * 256 + threadIdx.x;     // 448 blocks -> 114688 = 224*512
  if (idx < KP) {
    float bv = 0.f;
    int c = idx;
    if (c < 228)                  bv = b10[c] + b20[c];
    else if (c >= 256 && c < 367) bv = b01[c - 256] + b21[c - 256];
    else if (c >= 384 && c < 435) bv = b02[c - 384] + b12[c - 384];
    bbig[idx] = bv;
  }
  if (idx >= 224 * 512) return;
  const int ch = idx >> 9;                      // chunk 0..223
  const int e  = idx & 511;
  const int w  = ch / 28;
  const int s  = ch - w * 28;
  const int ks = (w < 4) ? A_KS[s] : B_KS[s];
  const int tl = (w < 4) ? A_T[s]  : B_T[s];
  const int tile = tile_id(w, tl);
  const int lane = e >> 3, el = e & 7;
  const int m = tile * 16 + (lane & 15);
  const int k = ks * 32 + (lane >> 4) * 8 + el;

  int bm, lm, bk, lk, Ck;
  bool mr, kr;
  if (m < 256)      { bm = 0; lm = m;       mr = lm < C0; }
  else if (m < 384) { bm = 1; lm = m - 256; mr = lm < C1; }
  else              { bm = 2; lm = m - 384; mr = lm < C2; }
  if (k < 256)      { bk = 0; lk = k;       Ck = C0; kr = lk < C0; }
  else if (k < 384) { bk = 1; lk = k - 256; Ck = C1; kr = lk < C1; }
  else              { bk = 2; lk = k - 384; Ck = C2; kr = lk < C2; }
  float v = 0.f;
  if (bm != bk && mr && kr) {
    const float* wp;
    if (bk == 0)      wp = (bm == 1) ? w01 : w02;
    else if (bk == 1) wp = (bm == 0) ? w10 : w12;
    else              wp = (bm == 0) ? w20 : w21;
    v = wp[lm * Ck + lk];
  }
  Wfrag[idx] = f2bf(v);
}

// ---- K-loop: register-resident weights x LDS h fragments (zero global) ----
template <int CLS>
__device__ __forceinline__ void kloop(const unsigned short (*cur)[RS],
                                      const short8 (&wreg)[28], f32x4 (&acc)[4][4],
                                      int l15, int lq) {
  short8 bq[4];
  #pragma unroll
  for (int s = 0; s < 28; ++s) {
    const int ks = CLS ? B_KS[s] : A_KS[s];
    const int t  = CLS ? B_T[s]  : A_T[s];
    const bool newks = (s == 0) || (ks != (CLS ? B_KS[s - 1] : A_KS[s - 1]));
    if (newks) {
      const int kcol = ks * 32 + (lq << 3);
      #pragma unroll
      for (int n = 0; n < 4; ++n)
        bq[n] = *reinterpret_cast<const short8*>(&cur[n * 16 + l15][kcol]);
    }
    #pragma unroll
    for (int n = 0; n < 4; ++n)
      acc[t][n] =
          __builtin_amdgcn_mfma_f32_16x16x32_bf16(wreg[s], bq[n], acc[t][n], 0, 0, 0);
  }
}

// ---- main: 2048 wgs x 512 thr (8 waves), 1 pixel-tile each (non-persistent).
//      Weights register-resident (one coalesced 28KB burst/wave, hidden under
//      staging); kloops touch only LDS + MFMA. ----
__global__ __launch_bounds__(512, 2) void crf_main(
    const float* __restrict__ x0, const float* __restrict__ x1,
    const float* __restrict__ x2,
    const unsigned short* __restrict__ Wfrag,
    const float* __restrict__ bbig,
    const float* __restrict__ pa,
    float* __restrict__ out) {
  __shared__ unsigned short hL[NPIX][RS];   // 58624 B -> 2 wg/CU
  const int lane = threadIdx.x & 63;
  const int wave = threadIdx.x >> 6;
  const int l15 = lane & 15;
  const int lq = lane >> 4;
  const float apar = pa[0];
  const int tile = blockIdx.x;
  const int b = tile >> 10;                 // 1024 tiles per batch image
  const int pp0 = (tile & 1023) << 6;

  // weights -> registers, once (28 contiguous 1KB chunks per wave, L2-hot)
  short8 wreg[28];
  {
    const unsigned short* wp = Wfrag + (((size_t)wave * 28) << 9) + (lane << 3);
    #pragma unroll
    for (int s = 0; s < 28; ++s)
      wreg[s] = *reinterpret_cast<const short8*>(wp + (s << 9));
  }

  // stage-in: x (fp32, channel-major) -> hL[pixel][padded channel] bf16.
  // Direct load->cvt->ds_write (short live ranges, no cross-kloop registers).
  #pragma unroll
  for (int g = 0; g < 7; ++g) {
    const int c0 = (wave + g * 8) * 8;
    short8 pk;
    #pragma unroll
    for (int cc = 0; cc < 8; ++cc) {
      const int c = c0 + cc;
      float v = 0.f;
      if (c < 228)
        v = __builtin_nontemporal_load(x0 + (((size_t)(b * C0 + c)) << 16) + pp0 + lane);
      else if (c >= 256 && c < 367)
        v = __builtin_nontemporal_load(x1 + (((size_t)(b * C1 + (c - 256))) << 16) + pp0 + lane);
      else if (c >= 384 && c < 435)
        v = __builtin_nontemporal_load(x2 + (((size_t)(b * C2 + (c - 384))) << 16) + pp0 + lane);
      pk[cc] = (short)f2bf(v);
    }
    *reinterpret_cast<short8*>(&hL[lane][c0]) = pk;
  }
  __syncthreads();

  #pragma unroll
  for (int it = 0; it < 2; ++it) {
    f32x4 acc[4][4];
    #pragma unroll
    for (int t = 0; t < 4; ++t)
      #pragma unroll
      for (int n = 0; n < 4; ++n) acc[t][n] = (f32x4){0.f, 0.f, 0.f, 0.f};

    if (wave < 4) kloop<0>(hL, wreg, acc, l15, lq);
    else          kloop<1>(hL, wreg, acc, l15, lq);
    __syncthreads();   // all kloop reads of hL complete before writeback

    if (it == 0) {
      // h1 = relu(h0 + prelu(binary + bias)); write back bf16 in place
      #pragma unroll
      for (int t = 0; t < 4; ++t) {
        if (t == 3 && wave >= 4) continue;  // class B owns 3 tiles
        const int cb = tile_id(wave, t) * 16 + (lq << 2);
        const f32x4 bias = *reinterpret_cast<const f32x4*>(bbig + cb);
        #pragma unroll
        for (int n = 0; n < 4; ++n) {
          const int p = n * 16 + l15;
          uint2v ho = *reinterpret_cast<const uint2v*>(&hL[p][cb]);
          const float hof[4] = {bf2f(ho[0] & 0xFFFFu), bf2f(ho[0] >> 16),
                                bf2f(ho[1] & 0xFFFFu), bf2f(ho[1] >> 16)};
          unsigned short nb[4];
          #pragma unroll
          for (int r = 0; r < 4; ++r) {
            float v = acc[t][n][r] + bias[r];
            float pr = (v >= 0.f) ? v : apar * v;
            nb[r] = f2bf(fmaxf(hof[r] + pr, 0.f));
          }
          uint2v pw;
          pw[0] = (unsigned)nb[0] | ((unsigned)nb[1] << 16);
          pw[1] = (unsigned)nb[2] | ((unsigned)nb[3] << 16);
          *reinterpret_cast<uint2v*>(&hL[p][cb]) = pw;
        }
      }
      __syncthreads();
    } else {
      // final: out = relu(h1 + prelu(binary + bias)) -> global fp32 (streaming)
      #pragma unroll
      for (int t = 0; t < 4; ++t) {
        if (t == 3 && wave >= 4) continue;
        const int cb = tile_id(wave, t) * 16 + (lq << 2);
        const f32x4 bias = *reinterpret_cast<const f32x4*>(bbig + cb);
        #pragma unroll
        for (int n = 0; n < 4; ++n) {
          const int p = n * 16 + l15;
          uint2v ho = *reinterpret_cast<const uint2v*>(&hL[p][cb]);
          const float hof[4] = {bf2f(ho[0] & 0xFFFFu), bf2f(ho[0] >> 16),
                                bf2f(ho[1] & 0xFFFFu), bf2f(ho[1] >> 16)};
          #pragma unroll
          for (int r = 0; r < 4; ++r) {
            const int c = cb + r;
            const int o = out_chan(c);
            float v = acc[t][n][r] + bias[r];
            float pr = (v >= 0.f) ? v : apar * v;
            float hn = fmaxf(hof[r] + pr, 0.f);
            if (o >= 0)
              __builtin_nontemporal_store(
                  hn, out + (((size_t)(b * 390 + o)) << 16) + pp0 + p);
          }
        }
      }
    }
  }
}

extern "C" void kernel_launch(void* const* d_in, const int* in_sizes, int n_in,
                              void* d_out, int out_size, void* d_ws, size_t ws_size,
                              hipStream_t stream) {
  const float* x0  = (const float*)d_in[0];
  const float* x1  = (const float*)d_in[1];
  const float* x2  = (const float*)d_in[2];
  const float* w01 = (const float*)d_in[3];
  const float* b01 = (const float*)d_in[4];
  const float* w02 = (const float*)d_in[5];
  const float* b02 = (const float*)d_in[6];
  const float* w10 = (const float*)d_in[7];
  const float* b10 = (const float*)d_in[8];
  const float* w12 = (const float*)d_in[9];
  const float* b12 = (const float*)d_in[10];
  const float* w20 = (const float*)d_in[11];
  const float* b20 = (const float*)d_in[12];
  const float* w21 = (const float*)d_in[13];
  const float* b21 = (const float*)d_in[14];
  const float* pa  = (const float*)d_in[15];

  unsigned short* Wfrag = (unsigned short*)d_ws;              // 224*512*2 = 229376 B
  float* bbig = (float*)((char*)d_ws + 224 * 512 * 2);        // +1792 B

  crf_prep<<<dim3(448), dim3(256), 0, stream>>>(
      w01, w02, w10, w12, w20, w21, b01, b02, b10, b12, b20, b21, Wfrag, bbig);
  crf_main<<<dim3(2048), dim3(512), 0, stream>>>(x0, x1, x2, Wfrag, bbig, pa,
                                                 (float*)d_out);
}

// Round 8
// 322.738 us; speedup vs baseline: 2.2441x; 1.1103x over previous
//
#include <hip/hip_runtime.h>
#include <stdint.h>

typedef __attribute__((ext_vector_type(8))) short short8;
typedef __attribute__((ext_vector_type(4))) float f32x4;
typedef __attribute__((ext_vector_type(2))) unsigned int uint2v;

#define C0 228
#define C1 111
#define C2 51
#define KP 448            // padded channels: [0,256)=b0, [256,384)=b1, [384,448)=b2
#define RS 458            // LDS row stride in bf16 elems; 229 dwords (odd) -> conflict-free
#define NPIX 32           // pixels per workgroup tile
#define NCHUNK (28 * 14)  // (mt,ks) weight chunks, 1KB each

__device__ __forceinline__ unsigned short f2bf(float f) {
  unsigned u = __float_as_uint(f);
  u += 0x7FFFu + ((u >> 16) & 1u);          // RNE
  return (unsigned short)(u >> 16);
}
__device__ __forceinline__ float bf2f(unsigned v) {
  return __uint_as_float(v << 16);
}
__device__ __forceinline__ int out_chan(int c) {
  if (c < 228) return c;
  if (c < 256) return -1;
  if (c < 367) return 228 + (c - 256);
  if (c < 384) return -1;
  if (c < 435) return 339 + (c - 384);
  return -1;
}

// ---- prep: weights -> fragment-contiguous 1KB chunks Wfrag[(mt*14+ks)*512],
//      lane l holds A[row=l&15][k=ks*32+(l>>4)*8+el]; + summed bias ----
__global__ void crf_prep(
    const float* __restrict__ w01, const float* __restrict__ w02,
    const float* __restrict__ w10, const float* __restrict__ w12,
    const float* __restrict__ w20, const float* __restrict__ w21,
    const float* __restrict__ b01, const float* __restrict__ b02,
    const float* __restrict__ b10, const float* __restrict__ b12,
    const float* __restrict__ b20, const float* __restrict__ b21,
    unsigned short* __restrict__ Wfrag, float* __restrict__ bbig) {
  int idx = blockIdx.x * 256 + threadIdx.x;     // 784 blocks = 392*512/256
  if (idx < KP) {
    float bv = 0.f;
    int c = idx;
    if (c < 228)                  bv = b10[c] + b20[c];
    else if (c >= 256 && c < 367) bv = b01[c - 256] + b21[c - 256];
    else if (c >= 384 && c < 435) bv = b02[c - 384] + b12[c - 384];
    bbig[idx] = bv;
  }
  if (idx >= NCHUNK * 512) return;
  const int ch = idx >> 9;                      // chunk 0..391
  const int e  = idx & 511;
  const int mt = ch / 14;
  const int ks = ch - mt * 14;
  const int lane = e >> 3, el = e & 7;
  const int m = mt * 16 + (lane & 15);
  const int k = ks * 32 + (lane >> 4) * 8 + el;

  int bm, lm, bk, lk, Ck;
  bool mr, kr;
  if (m < 256)      { bm = 0; lm = m;       mr = lm < C0; }
  else if (m < 384) { bm = 1; lm = m - 256; mr = lm < C1; }
  else              { bm = 2; lm = m - 384; mr = lm < C2; }
  if (k < 256)      { bk = 0; lk = k;       Ck = C0; kr = lk < C0; }
  else if (k < 384) { bk = 1; lk = k - 256; Ck = C1; kr = lk < C1; }
  else              { bk = 2; lk = k - 384; Ck = C2; kr = lk < C2; }
  float v = 0.f;
  if (bm != bk && mr && kr) {
    const float* wp;
    if (bk == 0)      wp = (bm == 1) ? w01 : w02;
    else if (bk == 1) wp = (bm == 0) ? w10 : w12;
    else              wp = (bm == 0) ? w20 : w21;
    v = wp[lm * Ck + lk];
  }
  Wfrag[idx] = f2bf(v);
}

// ---- K-loop: Wfrag coalesced gathers (L2) x LDS h fragments ----
__device__ __forceinline__ void kloop(const unsigned short (*cur)[RS],
                                      const unsigned short* __restrict__ Wfrag,
                                      f32x4 (&acc)[7][2], int wave,
                                      int lane, int l15, int lq) {
  #pragma unroll
  for (int ks = 0; ks < 14; ++ks) {
    const int kb = (ks < 8) ? 0 : ((ks < 12) ? 1 : 2);
    const int kcol = ks * 32 + (lq << 3);
    short8 bq[2];
    #pragma unroll
    for (int n = 0; n < 2; ++n)
      bq[n] = *reinterpret_cast<const short8*>(&cur[n * 16 + l15][kcol]);
    #pragma unroll
    for (int t = 0; t < 7; ++t) {
      const int bm = (t < 4) ? 0 : ((t < 6) ? 1 : 2);   // compile-time per t
      if (bm == kb) continue;           // diagonal (zero) block: skip
      const int mt = wave + 4 * t;
      const short8 aq = *reinterpret_cast<const short8*>(
          Wfrag + ((mt * 14 + ks) << 9) + (lane << 3));
      acc[t][0] = __builtin_amdgcn_mfma_f32_16x16x32_bf16(aq, bq[0], acc[t][0], 0, 0, 0);
      acc[t][1] = __builtin_amdgcn_mfma_f32_16x16x32_bf16(aq, bq[1], acc[t][1], 0, 0, 0);
    }
  }
}

// ---- main: 4096 wgs x 256 thr (4 waves), 32-px tile each, 4 wg/CU.
//      Four independent barrier-groups per CU interleave stage/compute phases. ----
__global__ __launch_bounds__(256, 4) void crf_main(
    const float* __restrict__ x0, const float* __restrict__ x1,
    const float* __restrict__ x2,
    const unsigned short* __restrict__ Wfrag,
    const float* __restrict__ bbig,
    const float* __restrict__ pa,
    float* __restrict__ out) {
  __shared__ unsigned short hL[NPIX][RS];   // 29312 B -> 4 wg/CU (117 KB)
  const int tid = threadIdx.x;
  const int lane = tid & 63;
  const int wave = tid >> 6;                // 0..3
  const int l15 = lane & 15;
  const int lq = lane >> 4;
  const float apar = pa[0];
  const int tile = blockIdx.x;
  const int b = tile >> 11;                 // 2048 tiles per batch image
  const int pp0 = (tile & 2047) << 5;       // 32 px per tile

  // ---- stage-in: px = tid&31, chl = tid>>5, channels c = chl*56 + j ----
  {
    const int px = tid & 31;
    const int chl = tid >> 5;
    #pragma unroll 8
    for (int j = 0; j < 56; ++j) {
      const int c = chl * 56 + j;
      float v = 0.f;
      if (c < 228)
        v = __builtin_nontemporal_load(x0 + (((size_t)(b * C0 + c)) << 16) + pp0 + px);
      else if (c >= 256 && c < 367)
        v = __builtin_nontemporal_load(x1 + (((size_t)(b * C1 + (c - 256))) << 16) + pp0 + px);
      else if (c >= 384 && c < 435)
        v = __builtin_nontemporal_load(x2 + (((size_t)(b * C2 + (c - 384))) << 16) + pp0 + px);
      hL[px][c] = f2bf(v);
    }
  }
  __syncthreads();

  #pragma unroll
  for (int it = 0; it < 2; ++it) {
    f32x4 acc[7][2];
    #pragma unroll
    for (int t = 0; t < 7; ++t) {
      acc[t][0] = (f32x4){0.f, 0.f, 0.f, 0.f};
      acc[t][1] = (f32x4){0.f, 0.f, 0.f, 0.f};
    }

    kloop(hL, Wfrag, acc, wave, lane, l15, lq);
    __syncthreads();   // all kloop reads of hL complete before writeback

    if (it == 0) {
      // h1 = relu(h0 + prelu(binary + bias)); write back bf16 in place
      #pragma unroll
      for (int t = 0; t < 7; ++t) {
        const int cb = (wave + 4 * t) * 16 + (lq << 2);
        const f32x4 bias = *reinterpret_cast<const f32x4*>(bbig + cb);
        #pragma unroll
        for (int n = 0; n < 2; ++n) {
          const int p = n * 16 + l15;
          uint2v ho = *reinterpret_cast<const uint2v*>(&hL[p][cb]);
          const float hof[4] = {bf2f(ho[0] & 0xFFFFu), bf2f(ho[0] >> 16),
                                bf2f(ho[1] & 0xFFFFu), bf2f(ho[1] >> 16)};
          unsigned short nb[4];
          #pragma unroll
          for (int r = 0; r < 4; ++r) {
            float v = acc[t][n][r] + bias[r];
            float pr = (v >= 0.f) ? v : apar * v;
            nb[r] = f2bf(fmaxf(hof[r] + pr, 0.f));
          }
          uint2v pw;
          pw[0] = (unsigned)nb[0] | ((unsigned)nb[1] << 16);
          pw[1] = (unsigned)nb[2] | ((unsigned)nb[3] << 16);
          *reinterpret_cast<uint2v*>(&hL[p][cb]) = pw;
        }
      }
      __syncthreads();
    } else {
      // final: out = relu(h1 + prelu(binary + bias)) -> global fp32 (streaming)
      #pragma unroll
      for (int t = 0; t < 7; ++t) {
        const int cb = (wave + 4 * t) * 16 + (lq << 2);
        const f32x4 bias = *reinterpret_cast<const f32x4*>(bbig + cb);
        #pragma unroll
        for (int n = 0; n < 2; ++n) {
          const int p = n * 16 + l15;
          uint2v ho = *reinterpret_cast<const uint2v*>(&hL[p][cb]);
          const float hof[4] = {bf2f(ho[0] & 0xFFFFu), bf2f(ho[0] >> 16),
                                bf2f(ho[1] & 0xFFFFu), bf2f(ho[1] >> 16)};
          #pragma unroll
          for (int r = 0; r < 4; ++r) {
            const int c = cb + r;
            const int o = out_chan(c);
            float v = acc[t][n][r] + bias[r];
            float pr = (v >= 0.f) ? v : apar * v;
            float hn = fmaxf(hof[r] + pr, 0.f);
            if (o >= 0)
              __builtin_nontemporal_store(
                  hn, out + (((size_t)(b * 390 + o)) << 16) + pp0 + p);
          }
        }
      }
    }
  }
}

extern "C" void kernel_launch(void* const* d_in, const int* in_sizes, int n_in,
                              void* d_out, int out_size, void* d_ws, size_t ws_size,
                              hipStream_t stream) {
  const float* x0  = (const float*)d_in[0];
  const float* x1  = (const float*)d_in[1];
  const float* x2  = (const float*)d_in[2];
  const float* w01 = (const float*)d_in[3];
  const float* b01 = (const float*)d_in[4];
  const float* w02 = (const float*)d_in[5];
  const float* b02 = (const float*)d_in[6];
  const float* w10 = (const float*)d_in[7];
  const float* b10 = (const float*)d_in[8];
  const float* w12 = (const float*)d_in[9];
  const float* b12 = (const float*)d_in[10];
  const float* w20 = (const float*)d_in[11];
  const float* b20 = (const float*)d_in[12];
  const float* w21 = (const float*)d_in[13];
  const float* b21 = (const float*)d_in[14];
  const float* pa  = (const float*)d_in[15];

  unsigned short* Wfrag = (unsigned short*)d_ws;                  // 392 KB
  float* bbig = (float*)((char*)d_ws + (size_t)NCHUNK * 512 * 2);

  crf_prep<<<dim3((NCHUNK * 512) / 256), dim3(256), 0, stream>>>(
      w01, w02, w10, w12, w20, w21, b01, b02, b10, b12, b20, b21, Wfrag, bbig);
  crf_main<<<dim3(4096), dim3(256), 0, stream>>>(x0, x1, x2, Wfrag, bbig, pa,
                                                 (float*)d_out);
}

// Round 9
// 263.294 us; speedup vs baseline: 2.7507x; 1.2258x over previous
//
#include <hip/hip_runtime.h>
#include <stdint.h>

typedef __attribute__((ext_vector_type(8))) short short8;
typedef __attribute__((ext_vector_type(4))) float f32x4;
typedef __attribute__((ext_vector_type(2))) unsigned int uint2v;

#define C0 228
#define C1 111
#define C2 51
#define KP 448              // padded channels: [0,256)=b0, [256,384)=b1, [384,448)=b2
#define TILE_SH 28672       // shorts per 64-px tile (64*448)
#define NCHUNKS 4
#define TPC 512             // tiles per chunk

// ---- balanced (tile,ks) schedule: 224 chunks = 8 waves x 28 slots (R4/R6-verified) ----
constexpr int A_KS[28] = {0,1,2,3,4,5,6,7,8,8,8,9,9,9,10,10,10,11,11,11,12,12,12,12,13,13,13,13};
constexpr int A_T [28] = {3,3,3,3,3,3,3,3,0,1,2,0,1,2, 0, 1, 2, 0, 1, 2, 0, 1, 2, 3, 0, 1, 2, 3};
constexpr int B_KS[28] = {0,0,1,1,2,2,3,3,4,4,5,5,6,6,7,7,8,8,9,9,10,10,11,11,12,12,13,13};
constexpr int B_T [28] = {1,2,1,2,1,2,1,2,1,2,1,2,1,2,1,2,0,2,0,2, 0, 2, 0, 2, 0, 1, 0, 1};

__host__ __device__ constexpr int tile_id(int w, int t) {
  return (w < 4) ? ((t < 3) ? (3 * w + t) : (16 + w))
                 : ((t == 0) ? (8 + w) : (t == 1) ? (16 + w) : (20 + w));
}

__device__ __forceinline__ unsigned short f2bf(float f) {
  unsigned u = __float_as_uint(f);
  u += 0x7FFFu + ((u >> 16) & 1u);          // RNE
  return (unsigned short)(u >> 16);
}
__device__ __forceinline__ float bf2f(unsigned v) {
  return __uint_as_float(v << 16);
}
__device__ __forceinline__ int out_chan(int c) {
  if (c < 228) return c;
  if (c < 256) return -1;
  if (c < 367) return 228 + (c - 256);
  if (c < 384) return -1;
  if (c < 435) return 339 + (c - 384);
  return -1;
}
// swizzled short-index of the 4-short group at (row p, channel cb) ; cb % 4 == 0
__device__ __forceinline__ int swz8(int p, int cb) {
  return p * 448 + ((((cb >> 3) ^ (p & 7))) << 3) + (cb & 7);
}

// ---- prep: weights -> schedule-ordered 1KB fragment chunks + summed bias ----
__global__ void crf_prep(
    const float* __restrict__ w01, const float* __restrict__ w02,
    const float* __restrict__ w10, const float* __restrict__ w12,
    const float* __restrict__ w20, const float* __restrict__ w21,
    const float* __restrict__ b01, const float* __restrict__ b02,
    const float* __restrict__ b10, const float* __restrict__ b12,
    const float* __restrict__ b20, const float* __restrict__ b21,
    unsigned short* __restrict__ Wfrag, float* __restrict__ bbig) {
  int idx = blockIdx.x * 256 + threadIdx.x;     // 448 blocks -> 224*512
  if (idx < KP) {
    float bv = 0.f;
    int c = idx;
    if (c < 228)                  bv = b10[c] + b20[c];
    else if (c >= 256 && c < 367) bv = b01[c - 256] + b21[c - 256];
    else if (c >= 384 && c < 435) bv = b02[c - 384] + b12[c - 384];
    bbig[idx] = bv;
  }
  if (idx >= 224 * 512) return;
  const int ch = idx >> 9;
  const int e  = idx & 511;
  const int w  = ch / 28;
  const int s  = ch - w * 28;
  const int ks = (w < 4) ? A_KS[s] : B_KS[s];
  const int tl = (w < 4) ? A_T[s]  : B_T[s];
  const int tile = tile_id(w, tl);
  const int lane = e >> 3, el = e & 7;
  const int m = tile * 16 + (lane & 15);
  const int k = ks * 32 + (lane >> 4) * 8 + el;

  int bm, lm, bk, lk, Ck;
  bool mr, kr;
  if (m < 256)      { bm = 0; lm = m;       mr = lm < C0; }
  else if (m < 384) { bm = 1; lm = m - 256; mr = lm < C1; }
  else              { bm = 2; lm = m - 384; mr = lm < C2; }
  if (k < 256)      { bk = 0; lk = k;       Ck = C0; kr = lk < C0; }
  else if (k < 384) { bk = 1; lk = k - 256; Ck = C1; kr = lk < C1; }
  else              { bk = 2; lk = k - 384; Ck = C2; kr = lk < C2; }
  float v = 0.f;
  if (bm != bk && mr && kr) {
    const float* wp;
    if (bk == 0)      wp = (bm == 1) ? w01 : w02;
    else if (bk == 1) wp = (bm == 0) ? w10 : w12;
    else              wp = (bm == 0) ? w20 : w21;
    v = wp[lm * Ck + lk];
  }
  Wfrag[idx] = f2bf(v);
}

// ---- xt pass: x (fp32 ch-major) -> xt[tile][px][ch] bf16, swizzle baked.
//      1024 wgs x 256 thr per chunk; wg = half a 64-px tile. Pure streaming. ----
__global__ __launch_bounds__(256, 8) void crf_xt(
    const float* __restrict__ x0, const float* __restrict__ x1,
    const float* __restrict__ x2, unsigned short* __restrict__ xt, int chunk) {
  const int tile_l = blockIdx.x >> 1;       // 0..511
  const int ph = blockIdx.x & 1;            // tile half
  const int g = chunk * TPC + tile_l;
  const int b = g >> 10;
  const int pp0 = (g & 1023) << 6;
  const int tid = threadIdx.x;
  const int pxq = tid & 7;                  // px quad within half
  const int chb0 = tid >> 3;                // 0..31
  unsigned short* dst = xt + (size_t)tile_l * TILE_SH;
  const int p0 = ph * 32 + pxq * 4;         // tile-local row of first px

  #pragma unroll
  for (int k = 0; k < 2; ++k) {
    const int blk = chb0 + (k << 5);        // 16B channel block (8 ch)
    if (blk >= 56) break;
    f32x4 v[8];
    #pragma unroll
    for (int cc = 0; cc < 8; ++cc) {
      const int c = blk * 8 + cc;
      v[cc] = (f32x4){0.f, 0.f, 0.f, 0.f};
      if (c < 228)
        v[cc] = *(const f32x4*)(x0 + (((size_t)(b * C0 + c)) << 16) + pp0 + p0);
      else if (c >= 256 && c < 367)
        v[cc] = *(const f32x4*)(x1 + (((size_t)(b * C1 + (c - 256))) << 16) + pp0 + p0);
      else if (c >= 384 && c < 435)
        v[cc] = *(const f32x4*)(x2 + (((size_t)(b * C2 + (c - 384))) << 16) + pp0 + p0);
    }
    #pragma unroll
    for (int px = 0; px < 4; ++px) {
      const int p = p0 + px;
      short8 pk;
      #pragma unroll
      for (int cc = 0; cc < 8; ++cc) pk[cc] = (short)f2bf(v[cc][px]);
      *reinterpret_cast<short8*>(dst + p * 448 + ((blk ^ (p & 7)) << 3)) = pk;
    }
  }
}

// ---- K-loop: Wfrag linear chunks (L2) x swizzled LDS h fragments ----
template <int CLS>
__device__ __forceinline__ void kloop(const unsigned short* __restrict__ hL,
                                      const unsigned short* __restrict__ wp,
                                      f32x4 (&acc)[4][4], int l15, int lq) {
  short8 bq[4];
  #pragma unroll
  for (int s = 0; s < 28; ++s) {
    const int ks = CLS ? B_KS[s] : A_KS[s];
    const int t  = CLS ? B_T[s]  : A_T[s];
    const bool newks = (s == 0) || (ks != (CLS ? B_KS[s - 1] : A_KS[s - 1]));
    if (newks) {
      #pragma unroll
      for (int n = 0; n < 4; ++n) {
        const int p = n * 16 + l15;
        bq[n] = *reinterpret_cast<const short8*>(
            hL + p * 448 + (((ks * 4 + lq) ^ (p & 7)) << 3));
      }
    }
    const short8 aq = *reinterpret_cast<const short8*>(wp + (s << 9));
    #pragma unroll
    for (int n = 0; n < 4; ++n)
      acc[t][n] =
          __builtin_amdgcn_mfma_f32_16x16x32_bf16(aq, bq[n], acc[t][n], 0, 0, 0);
  }
}

// ---- main: per chunk 512 wgs x 512 thr (8 waves), 2 wg/CU.
//      Stage = 7 global_load_lds dwordx4/thread (zero VALU). ----
__global__ __launch_bounds__(512, 4) void crf_main(
    const unsigned short* __restrict__ xt,
    const unsigned short* __restrict__ Wfrag,
    const float* __restrict__ bbig,
    const float* __restrict__ pa,
    float* __restrict__ out, int chunk) {
  __shared__ unsigned short hL[TILE_SH];    // 57344 B dense, swizzled layout
  const int tid = threadIdx.x;
  const int lane = tid & 63;
  const int wave = tid >> 6;
  const int l15 = lane & 15;
  const int lq = lane >> 4;
  const float apar = pa[0];
  const int g = chunk * TPC + blockIdx.x;
  const int b = g >> 10;
  const int pp0 = (g & 1023) << 6;

  // ---- stage: pure DMA xt tile -> LDS (layout identical, swizzle pre-baked) ----
  {
    const unsigned short* src = xt + (size_t)blockIdx.x * TILE_SH;
    typedef const __attribute__((address_space(1))) unsigned int* gdw_t;
    typedef __attribute__((address_space(3))) unsigned int* ldw_t;
    #pragma unroll
    for (int r = 0; r < 7; ++r) {
      const int off = r * 4096 + tid * 8;   // shorts; 16B per thread per round
      __builtin_amdgcn_global_load_lds((gdw_t)(const void*)(src + off),
                                       (ldw_t)(void*)(hL + off), 16, 0, 0);
    }
  }
  __syncthreads();

  const unsigned short* wp = Wfrag + (((size_t)wave * 28) << 9) + (lane << 3);

  #pragma unroll
  for (int it = 0; it < 2; ++it) {
    f32x4 acc[4][4];
    #pragma unroll
    for (int t = 0; t < 4; ++t)
      #pragma unroll
      for (int n = 0; n < 4; ++n) acc[t][n] = (f32x4){0.f, 0.f, 0.f, 0.f};

    if (wave < 4) kloop<0>(hL, wp, acc, l15, lq);
    else          kloop<1>(hL, wp, acc, l15, lq);
    __syncthreads();   // kloop reads of hL complete before writeback

    if (it == 0) {
      // h1 = relu(h0 + prelu(binary + bias)); write back bf16 in place (swizzled)
      #pragma unroll
      for (int t = 0; t < 4; ++t) {
        if (t == 3 && wave >= 4) continue;
        const int cb = tile_id(wave, t) * 16 + (lq << 2);
        const f32x4 bias = *reinterpret_cast<const f32x4*>(bbig + cb);
        #pragma unroll
        for (int n = 0; n < 4; ++n) {
          const int p = n * 16 + l15;
          unsigned short* hp = hL + swz8(p, cb);
          uint2v ho = *reinterpret_cast<const uint2v*>(hp);
          const float hof[4] = {bf2f(ho[0] & 0xFFFFu), bf2f(ho[0] >> 16),
                                bf2f(ho[1] & 0xFFFFu), bf2f(ho[1] >> 16)};
          unsigned short nb[4];
          #pragma unroll
          for (int r = 0; r < 4; ++r) {
            float v = acc[t][n][r] + bias[r];
            float pr = (v >= 0.f) ? v : apar * v;
            nb[r] = f2bf(fmaxf(hof[r] + pr, 0.f));
          }
          uint2v pw;
          pw[0] = (unsigned)nb[0] | ((unsigned)nb[1] << 16);
          pw[1] = (unsigned)nb[2] | ((unsigned)nb[3] << 16);
          *reinterpret_cast<uint2v*>(hp) = pw;
        }
      }
      __syncthreads();
    } else {
      // final: out = relu(h1 + prelu(binary + bias)) -> global fp32 (streaming)
      #pragma unroll
      for (int t = 0; t < 4; ++t) {
        if (t == 3 && wave >= 4) continue;
        const int cb = tile_id(wave, t) * 16 + (lq << 2);
        const f32x4 bias = *reinterpret_cast<const f32x4*>(bbig + cb);
        #pragma unroll
        for (int n = 0; n < 4; ++n) {
          const int p = n * 16 + l15;
          uint2v ho = *reinterpret_cast<const uint2v*>(hL + swz8(p, cb));
          const float hof[4] = {bf2f(ho[0] & 0xFFFFu), bf2f(ho[0] >> 16),
                                bf2f(ho[1] & 0xFFFFu), bf2f(ho[1] >> 16)};
          #pragma unroll
          for (int r = 0; r < 4; ++r) {
            const int c = cb + r;
            const int o = out_chan(c);
            float v = acc[t][n][r] + bias[r];
            float pr = (v >= 0.f) ? v : apar * v;
            float hn = fmaxf(hof[r] + pr, 0.f);
            if (o >= 0)
              __builtin_nontemporal_store(
                  hn, out + (((size_t)(b * 390 + o)) << 16) + pp0 + p);
          }
        }
      }
    }
  }
}

extern "C" void kernel_launch(void* const* d_in, const int* in_sizes, int n_in,
                              void* d_out, int out_size, void* d_ws, size_t ws_size,
                              hipStream_t stream) {
  const float* x0  = (const float*)d_in[0];
  const float* x1  = (const float*)d_in[1];
  const float* x2  = (const float*)d_in[2];
  const float* w01 = (const float*)d_in[3];
  const float* b01 = (const float*)d_in[4];
  const float* w02 = (const float*)d_in[5];
  const float* b02 = (const float*)d_in[6];
  const float* w10 = (const float*)d_in[7];
  const float* b10 = (const float*)d_in[8];
  const float* w12 = (const float*)d_in[9];
  const float* b12 = (const float*)d_in[10];
  const float* w20 = (const float*)d_in[11];
  const float* b20 = (const float*)d_in[12];
  const float* w21 = (const float*)d_in[13];
  const float* b21 = (const float*)d_in[14];
  const float* pa  = (const float*)d_in[15];

  unsigned short* Wfrag = (unsigned short*)d_ws;                    // 229376 B
  float* bbig = (float*)((char*)d_ws + 229376);                     // 1792 B
  unsigned short* xt = (unsigned short*)((char*)d_ws + 231424);     // 29.36 MB

  crf_prep<<<dim3(448), dim3(256), 0, stream>>>(
      w01, w02, w10, w12, w20, w21, b01, b02, b10, b12, b20, b21, Wfrag, bbig);
  for (int c = 0; c < NCHUNKS; ++c) {
    crf_xt<<<dim3(TPC * 2), dim3(256), 0, stream>>>(x0, x1, x2, xt, c);
    crf_main<<<dim3(TPC), dim3(512), 0, stream>>>(xt, Wfrag, bbig, pa,
                                                  (float*)d_out, c);
  }
}

// Round 10
// 220.869 us; speedup vs baseline: 3.2791x; 1.1921x over previous
//
#include <hip/hip_runtime.h>
#include <stdint.h>

typedef __attribute__((ext_vector_type(8))) short short8;
typedef __attribute__((ext_vector_type(4))) float f32x4;
typedef __attribute__((ext_vector_type(2))) unsigned int uint2v;

#define C0 228
#define C1 111
#define C2 51
#define KP 448              // padded channels: [0,256)=b0, [256,384)=b1, [384,448)=b2
#define TILE_SH 28672       // shorts per 64-px tile (64*448), dense swizzled layout

// ---- balanced (tile,ks) schedule: 224 chunks = 8 waves x 28 slots (R4/R6/R9-verified) ----
constexpr int A_KS[28] = {0,1,2,3,4,5,6,7,8,8,8,9,9,9,10,10,10,11,11,11,12,12,12,12,13,13,13,13};
constexpr int A_T [28] = {3,3,3,3,3,3,3,3,0,1,2,0,1,2, 0, 1, 2, 0, 1, 2, 0, 1, 2, 3, 0, 1, 2, 3};
constexpr int B_KS[28] = {0,0,1,1,2,2,3,3,4,4,5,5,6,6,7,7,8,8,9,9,10,10,11,11,12,12,13,13};
constexpr int B_T [28] = {1,2,1,2,1,2,1,2,1,2,1,2,1,2,1,2,0,2,0,2, 0, 2, 0, 2, 0, 1, 0, 1};

__host__ __device__ constexpr int tile_id(int w, int t) {
  return (w < 4) ? ((t < 3) ? (3 * w + t) : (16 + w))
                 : ((t == 0) ? (8 + w) : (t == 1) ? (16 + w) : (20 + w));
}

__device__ __forceinline__ unsigned short f2bf(float f) {
  unsigned u = __float_as_uint(f);
  u += 0x7FFFu + ((u >> 16) & 1u);          // RNE
  return (unsigned short)(u >> 16);
}
__device__ __forceinline__ float bf2f(unsigned v) {
  return __uint_as_float(v << 16);
}
__device__ __forceinline__ int out_chan(int c) {
  if (c < 228) return c;
  if (c < 256) return -1;
  if (c < 367) return 228 + (c - 256);
  if (c < 384) return -1;
  if (c < 435) return 339 + (c - 384);
  return -1;
}
// swizzled short-index of the group at (row p, channel cb); XOR on 16B block id
__device__ __forceinline__ int swz8(int p, int cb) {
  return p * 448 + (((cb >> 3) ^ (p & 7)) << 3) + (cb & 7);
}

// ---- prep: weights -> schedule-ordered 1KB fragment chunks + summed bias (R9-verified) ----
__global__ void crf_prep(
    const float* __restrict__ w01, const float* __restrict__ w02,
    const float* __restrict__ w10, const float* __restrict__ w12,
    const float* __restrict__ w20, const float* __restrict__ w21,
    const float* __restrict__ b01, const float* __restrict__ b02,
    const float* __restrict__ b10, const float* __restrict__ b12,
    const float* __restrict__ b20, const float* __restrict__ b21,
    unsigned short* __restrict__ Wfrag, float* __restrict__ bbig) {
  int idx = blockIdx.x * 256 + threadIdx.x;     // 448 blocks -> 224*512
  if (idx < KP) {
    float bv = 0.f;
    int c = idx;
    if (c < 228)                  bv = b10[c] + b20[c];
    else if (c >= 256 && c < 367) bv = b01[c - 256] + b21[c - 256];
    else if (c >= 384 && c < 435) bv = b02[c - 384] + b12[c - 384];
    bbig[idx] = bv;
  }
  if (idx >= 224 * 512) return;
  const int ch = idx >> 9;
  const int e  = idx & 511;
  const int w  = ch / 28;
  const int s  = ch - w * 28;
  const int ks = (w < 4) ? A_KS[s] : B_KS[s];
  const int tl = (w < 4) ? A_T[s]  : B_T[s];
  const int tile = tile_id(w, tl);
  const int lane = e >> 3, el = e & 7;
  const int m = tile * 16 + (lane & 15);
  const int k = ks * 32 + (lane >> 4) * 8 + el;

  int bm, lm, bk, lk, Ck;
  bool mr, kr;
  if (m < 256)      { bm = 0; lm = m;       mr = lm < C0; }
  else if (m < 384) { bm = 1; lm = m - 256; mr = lm < C1; }
  else              { bm = 2; lm = m - 384; mr = lm < C2; }
  if (k < 256)      { bk = 0; lk = k;       Ck = C0; kr = lk < C0; }
  else if (k < 384) { bk = 1; lk = k - 256; Ck = C1; kr = lk < C1; }
  else              { bk = 2; lk = k - 384; Ck = C2; kr = lk < C2; }
  float v = 0.f;
  if (bm != bk && mr && kr) {
    const float* wp;
    if (bk == 0)      wp = (bm == 1) ? w01 : w02;
    else if (bk == 1) wp = (bm == 0) ? w10 : w12;
    else              wp = (bm == 0) ? w20 : w21;
    v = wp[lm * Ck + lk];
  }
  Wfrag[idx] = f2bf(v);
}

__device__ __forceinline__ f32x4 ldx4(const float* __restrict__ x0,
                                      const float* __restrict__ x1,
                                      const float* __restrict__ x2,
                                      int b, int c, int off) {
  if (c < 228)
    return __builtin_nontemporal_load(
        reinterpret_cast<const f32x4*>(x0 + (((size_t)(b * C0 + c)) << 16) + off));
  if (c >= 256 && c < 367)
    return __builtin_nontemporal_load(
        reinterpret_cast<const f32x4*>(x1 + (((size_t)(b * C1 + (c - 256))) << 16) + off));
  if (c >= 384 && c < 435)
    return __builtin_nontemporal_load(
        reinterpret_cast<const f32x4*>(x2 + (((size_t)(b * C2 + (c - 384))) << 16) + off));
  return (f32x4){0.f, 0.f, 0.f, 0.f};
}

// ---- K-loop: Wfrag linear 1KB chunks (L2) x swizzled LDS h fragments (R9-verified) ----
template <int CLS>
__device__ __forceinline__ void kloop(const unsigned short* __restrict__ hL,
                                      const unsigned short* __restrict__ wp,
                                      f32x4 (&acc)[4][4], int l15, int lq) {
  short8 bq[4];
  #pragma unroll
  for (int s = 0; s < 28; ++s) {
    const int ks = CLS ? B_KS[s] : A_KS[s];
    const int t  = CLS ? B_T[s]  : A_T[s];
    const bool newks = (s == 0) || (ks != (CLS ? B_KS[s - 1] : A_KS[s - 1]));
    if (newks) {
      #pragma unroll
      for (int n = 0; n < 4; ++n) {
        const int p = n * 16 + l15;
        bq[n] = *reinterpret_cast<const short8*>(
            hL + p * 448 + (((ks * 4 + lq) ^ (p & 7)) << 3));
      }
    }
    const short8 aq = *reinterpret_cast<const short8*>(wp + (s << 9));
    #pragma unroll
    for (int n = 0; n < 4; ++n)
      acc[t][n] =
          __builtin_amdgcn_mfma_f32_16x16x32_bf16(aq, bq[n], acc[t][n], 0, 0, 0);
  }
}

// ---- main: 2048 wgs x 512 thr (8 waves), 64-px tile, 2 wg/CU (independent
//      barrier groups). Vectorized f32x4 stage (14 VMEM/thread), swizzled LDS. ----
__global__ __launch_bounds__(512, 4) void crf_main(
    const float* __restrict__ x0, const float* __restrict__ x1,
    const float* __restrict__ x2,
    const unsigned short* __restrict__ Wfrag,
    const float* __restrict__ bbig,
    const float* __restrict__ pa,
    float* __restrict__ out) {
  __shared__ unsigned short hL[TILE_SH];    // 57344 B dense swizzled -> 2 wg/CU
  const int tid = threadIdx.x;
  const int lane = tid & 63;
  const int wave = tid >> 6;
  const int l15 = lane & 15;
  const int lq = lane >> 4;
  const float apar = pa[0];
  const int tile = blockIdx.x;
  const int b = tile >> 10;                 // 1024 tiles per batch image
  const int pp0 = (tile & 1023) << 6;

  // ---- stage: lane = (px-quad q, ch-pair) ; 14 f32x4 nt-loads + 28 swizzled b32 writes ----
  {
    const int q = lane & 15;                // px 4q..4q+3
    const int cp = (lane >> 4) << 1;        // 0,2,4,6
    #pragma unroll
    for (int j = 0; j < 7; ++j) {
      const int c = j * 64 + wave * 8 + cp; // even; c,c+1 share a 16B block
      const f32x4 v0 = ldx4(x0, x1, x2, b, c,     pp0 + 4 * q);
      const f32x4 v1 = ldx4(x0, x1, x2, b, c + 1, pp0 + 4 * q);
      #pragma unroll
      for (int e = 0; e < 4; ++e) {
        const int p = 4 * q + e;
        const unsigned pk =
            (unsigned)f2bf(v0[e]) | ((unsigned)f2bf(v1[e]) << 16);
        *reinterpret_cast<unsigned*>(hL + swz8(p, c)) = pk;
      }
    }
  }
  __syncthreads();

  const unsigned short* wp = Wfrag + (((size_t)wave * 28) << 9) + (lane << 3);

  #pragma unroll
  for (int it = 0; it < 2; ++it) {
    f32x4 acc[4][4];
    #pragma unroll
    for (int t = 0; t < 4; ++t)
      #pragma unroll
      for (int n = 0; n < 4; ++n) acc[t][n] = (f32x4){0.f, 0.f, 0.f, 0.f};

    __builtin_amdgcn_s_setprio(1);
    if (wave < 4) kloop<0>(hL, wp, acc, l15, lq);
    else          kloop<1>(hL, wp, acc, l15, lq);
    __builtin_amdgcn_s_setprio(0);
    __syncthreads();   // kloop reads of hL complete before writeback

    if (it == 0) {
      // h1 = relu(h0 + prelu(binary + bias)); write back bf16 in place (swizzled)
      #pragma unroll
      for (int t = 0; t < 4; ++t) {
        if (t == 3 && wave >= 4) continue;
        const int cb = tile_id(wave, t) * 16 + (lq << 2);
        const f32x4 bias = *reinterpret_cast<const f32x4*>(bbig + cb);
        #pragma unroll
        for (int n = 0; n < 4; ++n) {
          const int p = n * 16 + l15;
          unsigned short* hp = hL + swz8(p, cb);
          uint2v ho = *reinterpret_cast<const uint2v*>(hp);
          const float hof[4] = {bf2f(ho[0] & 0xFFFFu), bf2f(ho[0] >> 16),
                                bf2f(ho[1] & 0xFFFFu), bf2f(ho[1] >> 16)};
          unsigned short nb[4];
          #pragma unroll
          for (int r = 0; r < 4; ++r) {
            float v = acc[t][n][r] + bias[r];
            float pr = (v >= 0.f) ? v : apar * v;
            nb[r] = f2bf(fmaxf(hof[r] + pr, 0.f));
          }
          uint2v pw;
          pw[0] = (unsigned)nb[0] | ((unsigned)nb[1] << 16);
          pw[1] = (unsigned)nb[2] | ((unsigned)nb[3] << 16);
          *reinterpret_cast<uint2v*>(hp) = pw;
        }
      }
      __syncthreads();
    } else {
      // final: out = relu(h1 + prelu(binary + bias)) -> global fp32 (streaming)
      #pragma unroll
      for (int t = 0; t < 4; ++t) {
        if (t == 3 && wave >= 4) continue;
        const int cb = tile_id(wave, t) * 16 + (lq << 2);
        const f32x4 bias = *reinterpret_cast<const f32x4*>(bbig + cb);
        #pragma unroll
        for (int n = 0; n < 4; ++n) {
          const int p = n * 16 + l15;
          uint2v ho = *reinterpret_cast<const uint2v*>(hL + swz8(p, cb));
          const float hof[4] = {bf2f(ho[0] & 0xFFFFu), bf2f(ho[0] >> 16),
                                bf2f(ho[1] & 0xFFFFu), bf2f(ho[1] >> 16)};
          #pragma unroll
          for (int r = 0; r < 4; ++r) {
            const int c = cb + r;
            const int o = out_chan(c);
            float v = acc[t][n][r] + bias[r];
            float pr = (v >= 0.f) ? v : apar * v;
            float hn = fmaxf(hof[r] + pr, 0.f);
            if (o >= 0)
              __builtin_nontemporal_store(
                  hn, out + (((size_t)(b * 390 + o)) << 16) + pp0 + p);
          }
        }
      }
    }
  }
}

extern "C" void kernel_launch(void* const* d_in, const int* in_sizes, int n_in,
                              void* d_out, int out_size, void* d_ws, size_t ws_size,
                              hipStream_t stream) {
  const float* x0  = (const float*)d_in[0];
  const float* x1  = (const float*)d_in[1];
  const float* x2  = (const float*)d_in[2];
  const float* w01 = (const float*)d_in[3];
  const float* b01 = (const float*)d_in[4];
  const float* w02 = (const float*)d_in[5];
  const float* b02 = (const float*)d_in[6];
  const float* w10 = (const float*)d_in[7];
  const float* b10 = (const float*)d_in[8];
  const float* w12 = (const float*)d_in[9];
  const float* b12 = (const float*)d_in[10];
  const float* w20 = (const float*)d_in[11];
  const float* b20 = (const float*)d_in[12];
  const float* w21 = (const float*)d_in[13];
  const float* b21 = (const float*)d_in[14];
  const float* pa  = (const float*)d_in[15];

  unsigned short* Wfrag = (unsigned short*)d_ws;              // 224*512*2 = 229376 B
  float* bbig = (float*)((char*)d_ws + 229376);               // +1792 B

  crf_prep<<<dim3(448), dim3(256), 0, stream>>>(
      w01, w02, w10, w12, w20, w21, b01, b02, b10, b12, b20, b21, Wfrag, bbig);
  crf_main<<<dim3(2048), dim3(512), 0, stream>>>(x0, x1, x2, Wfrag, bbig, pa,
                                                 (float*)d_out);
}